// Round 5
// baseline (5058.882 us; speedup 1.0000x reference)
//
#include <hip/hip_runtime.h>
#include <stdint.h>

#define BATCH 4
#define NPTS  8192
#define CFEAT 64
#define MCENT 2048
#define NCENT (BATCH * MCENT)
#define KMAX  64
#define NEGV  -1e30f

// Exact-rounding squared distance, matching numpy's ((dx*dx+dy*dy)+dz*dz)
// with NO fma contraction (discrete neighbor selection requires bit parity).
__device__ __forceinline__ float dist2(float ax, float ay, float az,
                                       float bx, float by, float bz) {
    float dx = __fsub_rn(ax, bx);
    float dy = __fsub_rn(ay, by);
    float dz = __fsub_rn(az, bz);
    return __fadd_rn(__fadd_rn(__fmul_rn(dx, dx), __fmul_rn(dy, dy)),
                     __fmul_rn(dz, dz));
}

// DPP lane-permute helpers (VALU-latency cross-lane, vs ds_bpermute ~120cyc)
template <int CTRL>
__device__ __forceinline__ float dppf(float v) {
    return __int_as_float(__builtin_amdgcn_update_dpp(
        __float_as_int(v), __float_as_int(v), CTRL, 0xF, 0xF, false));
}
template <int CTRL>
__device__ __forceinline__ int dppi(int v) {
    return __builtin_amdgcn_update_dpp(v, v, CTRL, 0xF, 0xF, false);
}

// ---------------------------------------------------------------------------
// Kernel 1: farthest point sampling. One block per batch, 1024 threads,
// 8 points/thread.
//
// Rounds 2-4 post-mortem: ANY attempt to keep the 8192-point cloud in VGPRs
// (arrays or 64 named scalars) is defeated by the backend: VGPR_Count=48 <
// state size, i.e. the compiler re-executes the loop-invariant global loads
// every iteration instead of carrying them. Fix is structural: the cloud
// lives in LDS (96 KB < 160 KB/CU, 1 block/CU), re-read by DESIGN each iter:
// ds_read_b64 (xy) + ds_read_b32 (z), stride-1 per lane -> 2 lanes/bank =
// conflict-free. Per-iter LDS 96 KB ~= 768 cyc overlapping ~770 cyc VALU
// floor; 4 waves/SIMD hide LDS latency. Only mind0..7 stays in registers.
// ---------------------------------------------------------------------------
#define FPS_T   1024
#define FPS_W   (FPS_T / 64)

#define REP8(X) X(0) X(1) X(2) X(3) X(4) X(5) X(6) X(7)

__global__ __launch_bounds__(FPS_T, 1) void fps_kernel(const float* __restrict__ pos,
                                                       float* __restrict__ pos_s) {
    const int b = blockIdx.x;
    const float* pb = pos + b * NPTS * 3;
    const int t = threadIdx.x;          // 0..1023
    const int w = t >> 6;               // wave id 0..15

    __shared__ float2 sxy[NPTS];        // 64 KB
    __shared__ float  szz[NPTS];        // 32 KB
    __shared__ float  s_bv[2][FPS_W];
    __shared__ int    s_bp[2][FPS_W];

    // one-time stage of the cloud into LDS
    for (int e = t; e < NPTS; e += FPS_T) {
        float xx = pb[3 * e + 0];
        float yy = pb[3 * e + 1];
        float zz = pb[3 * e + 2];
        sxy[e] = make_float2(xx, yy);
        szz[e] = zz;
    }

#define FPS_DECL(i) float mind##i = 1e30f;
    REP8(FPS_DECL)
#undef FPS_DECL

    __syncthreads();

    float lx = sxy[0].x, ly = sxy[0].y, lz = szz[0];

    for (int m = 0; m < MCENT; ++m) {
        if (t == 0) {
            float* o = pos_s + (b * MCENT + m) * 3;
            o[0] = lx; o[1] = ly; o[2] = lz;
        }
        if (m + 1 == MCENT) break;      // final argmax discarded by the scan

        // update mind, local argmax over the 8 slots (i ascending == point
        // index ascending for fixed t; strict > keeps the lowest index).
        float bv = -1.0f; int bi = 0;
#define FPS_UPD(i) { int p = (i << 10) + t;                                   \
                     float2 xy = sxy[p]; float zz = szz[p];                   \
                     float d = dist2(xy.x, xy.y, zz, lx, ly, lz);             \
                     float mn = fminf(mind##i, d);                            \
                     mind##i = mn;                                            \
                     bool tk = mn > bv;                                       \
                     bv = tk ? mn : bv;                                       \
                     bi = tk ? i : bi; }
        REP8(FPS_UPD)
#undef FPS_UPD
        int bp = (bi << 10) + t;

        // wave64 argmax via DPP (combine idempotent: max, tie->min index)
#define RSTEP(C_) { float ov = dppf<C_>(bv); int op_ = dppi<C_>(bp);          \
                    bool tk = (ov > bv) || (ov == bv && op_ < bp);            \
                    bv = tk ? ov : bv; bp = tk ? op_ : bp; }
        RSTEP(0xB1)   // quad_perm [1,0,3,2]  : xor 1
        RSTEP(0x4E)   // quad_perm [2,3,0,1]  : xor 2
        RSTEP(0x141)  // row_half_mirror      : xor 4
        RSTEP(0x140)  // row_mirror           : xor 8
        RSTEP(0x142)  // row_bcast15          : rows 1,3 absorb rows 0,2
        RSTEP(0x143)  // row_bcast31          : upper half absorbs lower
#undef RSTEP

        const int par = m & 1;
        if ((t & 63) == 63) { s_bv[par][w] = bv; s_bp[par][w] = bp; }
        __syncthreads();

        // all threads redundantly pick the block winner (broadcast LDS reads)
        float gv = s_bv[par][0]; int gp = s_bp[par][0];
#pragma unroll
        for (int q = 1; q < FPS_W; ++q) {
            float ov = s_bv[par][q]; int op_ = s_bp[par][q];
            bool tk = (ov > gv) || (ov == gv && op_ < gp);
            gv = tk ? ov : gv; gp = tk ? op_ : gp;
        }
        float2 lxy = sxy[gp];
        lx = lxy.x; ly = lxy.y; lz = szz[gp];
    }
}

// ---------------------------------------------------------------------------
// Kernel 2: exact top-64 (by (d2, idx) u64 key) within ball r=0.4 via
// histogram radix-select + O(C^2) exact ranking. Downstream max-aggregation
// is order-invariant, but ranks reproduce lax.top_k order anyway.
// ---------------------------------------------------------------------------
#define KNN_CAP 320

__global__ __launch_bounds__(256) void knn_kernel(const float* __restrict__ pos,
                                                  const float* __restrict__ pos_s,
                                                  int* __restrict__ nidx,
                                                  float* __restrict__ nd2,
                                                  int* __restrict__ ncnt) {
    const int c = blockIdx.x;
    const int b = c >> 11;              // c / MCENT
    const float* pb = pos + b * NPTS * 3;
    const int t = threadIdx.x;

    const float cx = pos_s[c * 3 + 0];
    const float cy = pos_s[c * 3 + 1];
    const float cz = pos_s[c * 3 + 2];

    __shared__ int hist[64];
    __shared__ int s_B64, s_total, s_cnt;
    __shared__ unsigned long long cand[KNN_CAP];

    if (t < 64) hist[t] = 0;
    if (t == 0) s_cnt = 0;
    __syncthreads();

    float d2r[32];
#pragma unroll
    for (int i = 0; i < 32; ++i) {
        int p = (i << 8) + t;
        float d2 = dist2(cx, cy, cz, pb[3 * p + 0], pb[3 * p + 1], pb[3 * p + 2]);
        d2r[i] = d2;
        if (d2 <= 0.16f) {
            int bkt = (int)(d2 * 400.0f);      // monotone; 0.16f*400 < 64
            bkt = bkt > 63 ? 63 : bkt;
            atomicAdd(&hist[bkt], 1);
        }
    }
    __syncthreads();

    if (t == 0) {
        int cum = 0, B = -1;
#pragma unroll
        for (int j = 0; j < 64; ++j) {
            cum += hist[j];
            if (B < 0 && cum >= 64) B = j;
        }
        s_B64 = (B < 0) ? 63 : B;
        s_total = cum;
    }
    __syncthreads();

    const int B64 = s_B64;
#pragma unroll
    for (int i = 0; i < 32; ++i) {
        float d2 = d2r[i];
        if (d2 <= 0.16f) {
            int bkt = (int)(d2 * 400.0f);
            bkt = bkt > 63 ? 63 : bkt;
            if (bkt <= B64) {
                int slot = atomicAdd(&s_cnt, 1);
                if (slot < KNN_CAP) {
                    int p = (i << 8) + t;
                    cand[slot] = ((unsigned long long)__float_as_uint(d2) << 32)
                                 | (unsigned int)p;
                }
            }
        }
    }
    __syncthreads();

    const int C = s_cnt < KNN_CAP ? s_cnt : KNN_CAP;
    // exact rank: candidate set is downward-closed, so candidate rank ==
    // global in-ball rank. Broadcast LDS reads (wave-uniform j).
    for (int tc = t; tc < C; tc += 256) {
        unsigned long long my = cand[tc];
        int rank = 0;
        for (int j = 0; j < C; ++j) rank += (cand[j] < my) ? 1 : 0;
        if (rank < KMAX) {
            nidx[c * KMAX + rank] = (int)(my & 0xffffffffULL);
            nd2[c * KMAX + rank]  = __uint_as_float((unsigned int)(my >> 32));
        }
    }
    if (t == 0) ncnt[c] = s_total < KMAX ? s_total : KMAX;
}

// ---------------------------------------------------------------------------
// Kernel 3: fused gather + 2-layer MLP + masked max per centroid.
// ---------------------------------------------------------------------------
template <int K, int C1, int C2, int OUTOFF>
__global__ __launch_bounds__(256, 2) void mlp_kernel(
        const float* __restrict__ x, const float* __restrict__ pos,
        const float* __restrict__ pos_s,
        const int* __restrict__ nidx, const float* __restrict__ nd2,
        const int* __restrict__ ncnt,
        const float* __restrict__ W1, const float* __restrict__ B1,
        const float* __restrict__ W2, const float* __restrict__ B2,
        float* __restrict__ out, float r2) {
    const int c = blockIdx.x;
    const int b = c >> 11;
    const int t = threadIdx.x;

    __shared__ float F[K][68];      // [K][67] padded to 17 float4
    __shared__ float H[K][C1];
    __shared__ int   s_nbr[K];
    __shared__ int   s_valid[K];
    __shared__ float s_ctr[3];

    const int cntAll = ncnt[c];
    const int cnt = cntAll < K ? cntAll : K;
    if (t < 3) s_ctr[t] = pos_s[c * 3 + t];
    if (t < K) {
        bool ok = t < cnt;
        s_nbr[t]   = ok ? nidx[c * KMAX + t] : 0;
        s_valid[t] = ok && (nd2[c * KMAX + t] <= r2);
    }
    __syncthreads();

    // gather features: F[k] = [ x[nbr] (64) | pos[nbr]-ctr (3) | 0 pad ]
    for (int e = t; e < K * 17; e += 256) {
        int k = e / 17, q = e % 17;
        int nbr = s_nbr[k];
        bool ok = k < cnt;
        float4 val;
        if (q < 16) {
            const float4* xr = (const float4*)(x + (b * NPTS + nbr) * CFEAT);
            if (ok) val = xr[q];
            else { val.x = 0.f; val.y = 0.f; val.z = 0.f; val.w = 0.f; }
        } else {
            const float* pp = pos + (b * NPTS + nbr) * 3;
            val.x = ok ? pp[0] - s_ctr[0] : 0.f;
            val.y = ok ? pp[1] - s_ctr[1] : 0.f;
            val.z = ok ? pp[2] - s_ctr[2] : 0.f;
            val.w = 0.f;
        }
        ((float4*)&F[k][0])[q] = val;
    }
    __syncthreads();

    // layer 1: H[k][j] = relu(B1[j] + F[k]·W1[:,j])
    {
        constexpr int STR = 256 / C1;
        const int j  = t % C1;
        const int kb = t / C1;
        float w1c[68];
#pragma unroll
        for (int i = 0; i < 67; ++i) w1c[i] = W1[i * C1 + j];
        w1c[67] = 0.f;
        const float bj = B1[j];
        for (int k = kb; k < K; k += STR) {
            float acc = bj;
            const float4* fr = (const float4*)&F[k][0];
#pragma unroll
            for (int q = 0; q < 17; ++q) {
                float4 f = fr[q];
                acc = fmaf(f.x, w1c[4 * q + 0], acc);
                acc = fmaf(f.y, w1c[4 * q + 1], acc);
                acc = fmaf(f.z, w1c[4 * q + 2], acc);
                acc = fmaf(f.w, w1c[4 * q + 3], acc);
            }
            H[k][j] = fmaxf(acc, 0.f);
        }
    }
    __syncthreads();

    // layer 2 + masked max over neighbors
    if constexpr (C2 == 256) {
        const int j2 = t;
        float w2c[C1];
#pragma unroll
        for (int i = 0; i < C1; ++i) w2c[i] = W2[i * C2 + j2];
        const float bj = B2[j2];
        float omax = NEGV;
        for (int k = 0; k < K; ++k) {
            if (!s_valid[k]) continue;          // uniform branch
            float acc = bj;
            const float4* hr = (const float4*)&H[k][0];
#pragma unroll
            for (int q = 0; q < C1 / 4; ++q) {
                float4 h = hr[q];
                acc = fmaf(h.x, w2c[4 * q + 0], acc);
                acc = fmaf(h.y, w2c[4 * q + 1], acc);
                acc = fmaf(h.z, w2c[4 * q + 2], acc);
                acc = fmaf(h.w, w2c[4 * q + 3], acc);
            }
            omax = fmaxf(omax, fmaxf(acc, 0.f));
        }
        out[c * 384 + OUTOFF + j2] = omax;
    } else {
        // C2 == 128: 2 thread-groups split the k range, combine via LDS
        const int j2 = t % C2;
        const int g  = t / C2;
        __shared__ float pm[256];
        float w2c[C1];
#pragma unroll
        for (int i = 0; i < C1; ++i) w2c[i] = W2[i * C2 + j2];
        const float bj = B2[j2];
        float omax = NEGV;
        for (int k = g; k < K; k += 2) {
            if (!s_valid[k]) continue;
            float acc = bj;
            const float4* hr = (const float4*)&H[k][0];
#pragma unroll
            for (int q = 0; q < C1 / 4; ++q) {
                float4 h = hr[q];
                acc = fmaf(h.x, w2c[4 * q + 0], acc);
                acc = fmaf(h.y, w2c[4 * q + 1], acc);
                acc = fmaf(h.z, w2c[4 * q + 2], acc);
                acc = fmaf(h.w, w2c[4 * q + 3], acc);
            }
            omax = fmaxf(omax, fmaxf(acc, 0.f));
        }
        pm[t] = omax;
        __syncthreads();
        if (t < C2) out[c * 384 + OUTOFF + t] = fmaxf(pm[t], pm[t + C2]);
    }
}

extern "C" void kernel_launch(void* const* d_in, const int* in_sizes, int n_in,
                              void* d_out, int out_size, void* d_ws, size_t ws_size,
                              hipStream_t stream) {
    const float* x    = (const float*)d_in[0];
    const float* pos  = (const float*)d_in[1];
    const float* w1_0 = (const float*)d_in[2];
    const float* b1_0 = (const float*)d_in[3];
    const float* w1_1 = (const float*)d_in[4];
    const float* b1_1 = (const float*)d_in[5];
    const float* w2_0 = (const float*)d_in[6];
    const float* b2_0 = (const float*)d_in[7];
    const float* w2_1 = (const float*)d_in[8];
    const float* b2_1 = (const float*)d_in[9];

    float* out   = (float*)d_out;
    float* pos_s = out + NCENT * 384;          // second output, written by FPS

    char* ws = (char*)d_ws;
    int*   ncnt = (int*)ws;                                   // NCENT ints
    int*   nidx = (int*)(ws + NCENT * 4);                     // NCENT*64 ints
    float* nd2  = (float*)(ws + NCENT * 4 + NCENT * KMAX * 4);// NCENT*64 floats

    fps_kernel<<<BATCH, FPS_T, 0, stream>>>(pos, pos_s);
    knn_kernel<<<NCENT, 256, 0, stream>>>(pos, pos_s, nidx, nd2, ncnt);
    mlp_kernel<32, 64, 128, 0><<<NCENT, 256, 0, stream>>>(
        x, pos, pos_s, nidx, nd2, ncnt, w1_0, b1_0, w1_1, b1_1, out, 0.04f);
    mlp_kernel<64, 128, 256, 128><<<NCENT, 256, 0, stream>>>(
        x, pos, pos_s, nidx, nd2, ncnt, w2_0, b2_0, w2_1, b2_1, out, 0.16f);
}

// Round 6
// 4095.840 us; speedup vs baseline: 1.2351x; 1.2351x over previous
//
#include <hip/hip_runtime.h>
#include <stdint.h>

#define BATCH 4
#define NPTS  8192
#define CFEAT 64
#define MCENT 2048
#define NCENT (BATCH * MCENT)
#define KMAX  64
#define NEGV  -1e30f

// Exact-rounding squared distance, matching numpy's ((dx*dx+dy*dy)+dz*dz)
// with NO fma contraction (discrete neighbor selection requires bit parity).
__device__ __forceinline__ float dist2(float ax, float ay, float az,
                                       float bx, float by, float bz) {
    float dx = __fsub_rn(ax, bx);
    float dy = __fsub_rn(ay, by);
    float dz = __fsub_rn(az, bz);
    return __fadd_rn(__fadd_rn(__fmul_rn(dx, dx), __fmul_rn(dy, dy)),
                     __fmul_rn(dz, dz));
}

// DPP lane-permute helpers (VALU-latency cross-lane, vs ds_bpermute ~120cyc)
template <int CTRL>
__device__ __forceinline__ float dppf(float v) {
    return __int_as_float(__builtin_amdgcn_update_dpp(
        __float_as_int(v), __float_as_int(v), CTRL, 0xF, 0xF, false));
}
template <int CTRL>
__device__ __forceinline__ int dppi(int v) {
    return __builtin_amdgcn_update_dpp(v, v, CTRL, 0xF, 0xF, false);
}

// ---------------------------------------------------------------------------
// Kernel 1: farthest point sampling. One block per batch, 512 threads,
// 16 points/thread.
//
// Round-5 post-mortem: issue-bound (VALUBusy ~86% on the 4 active CUs),
// ~4600 cyc/iter. Cost = 2 LDS reads + addr math PER POINT (float2+float
// layout) + 16-entry per-wave scan. Fix: SoA float4 LDS (sx4/sy4/sz4);
// one ds_read_b128 covers 4 points' coordinate -> 16 points = 12 LDS inst,
// no per-point address math. 512 threads: 8 waves, scan is 8 entries.
// mind state is loop-carried (never demoted - verified rounds 3-5).
// ---------------------------------------------------------------------------
#define FPS_T   512
#define FPS_W   (FPS_T / 64)
#define NGRP    (NPTS / 4)          // 2048 float4 groups

__global__ __launch_bounds__(FPS_T, 2) void fps_kernel(const float* __restrict__ pos,
                                                       float* __restrict__ pos_s) {
    const int b = blockIdx.x;
    const float* pb = pos + b * NPTS * 3;
    const int t = threadIdx.x;          // 0..511
    const int w = t >> 6;               // wave id 0..7

    __shared__ float4 sx4[NGRP];        // 32 KB
    __shared__ float4 sy4[NGRP];        // 32 KB
    __shared__ float4 sz4[NGRP];        // 32 KB
    __shared__ float  s_bv[2][FPS_W];
    __shared__ int    s_bp[2][FPS_W];

    // stage + transpose: 12 consecutive floats = 4 points (48B stride keeps
    // 16B alignment for every e)
    {
        const float4* src = (const float4*)pb;
        for (int e = t; e < NGRP; e += FPS_T) {
            float4 va = src[3 * e + 0];
            float4 vb = src[3 * e + 1];
            float4 vc = src[3 * e + 2];
            sx4[e] = make_float4(va.x, va.w, vb.z, vc.y);
            sy4[e] = make_float4(va.y, vb.x, vb.w, vc.z);
            sz4[e] = make_float4(va.z, vb.y, vc.x, vc.w);
        }
    }

    float md0 = 1e30f, md1 = 1e30f, md2 = 1e30f, md3 = 1e30f;
    float md4 = 1e30f, md5 = 1e30f, md6 = 1e30f, md7 = 1e30f;
    float md8 = 1e30f, md9 = 1e30f, md10 = 1e30f, md11 = 1e30f;
    float md12 = 1e30f, md13 = 1e30f, md14 = 1e30f, md15 = 1e30f;

    __syncthreads();

    float lx = sx4[0].x, ly = sy4[0].x, lz = sz4[0].x;   // point 0

    for (int m = 0; m < MCENT; ++m) {
        if (t == 0) {
            float* o = pos_s + (b * MCENT + m) * 3;
            o[0] = lx; o[1] = ly; o[2] = lz;
        }
        if (m + 1 == MCENT) break;      // final argmax discarded by the scan

        float bv = -1.0f; int bp = 0;

        // group j covers points 4*(t+512j)..+3; ascending (j,q) == ascending
        // point index for fixed t; strict > keeps the lowest index.
#define FPS_PT(Q_, MD_, G_)                                                   \
        { float d = dist2(fx.Q_, fy.Q_, fz.Q_, lx, ly, lz);                   \
          float mn = fminf(MD_, d);                                           \
          MD_ = mn;                                                           \
          bool tk = mn > bv;                                                  \
          bv = tk ? mn : bv;                                                  \
          bp = tk ? 4 * (G_) + (&fx.x - &fx.x) : bp; }

#define FPS_GRP(J_, MA_, MB_, MC_, MD4_)                                      \
        { const int g = t + FPS_T * (J_);                                     \
          float4 fx = sx4[g], fy = sy4[g], fz = sz4[g];                       \
          { float d = dist2(fx.x, fy.x, fz.x, lx, ly, lz);                    \
            float mn = fminf(MA_, d); MA_ = mn;                               \
            bool tk = mn > bv; bv = tk ? mn : bv; bp = tk ? 4 * g + 0 : bp; } \
          { float d = dist2(fx.y, fy.y, fz.y, lx, ly, lz);                    \
            float mn = fminf(MB_, d); MB_ = mn;                               \
            bool tk = mn > bv; bv = tk ? mn : bv; bp = tk ? 4 * g + 1 : bp; } \
          { float d = dist2(fx.z, fy.z, fz.z, lx, ly, lz);                    \
            float mn = fminf(MC_, d); MC_ = mn;                               \
            bool tk = mn > bv; bv = tk ? mn : bv; bp = tk ? 4 * g + 2 : bp; } \
          { float d = dist2(fx.w, fy.w, fz.w, lx, ly, lz);                    \
            float mn = fminf(MD4_, d); MD4_ = mn;                             \
            bool tk = mn > bv; bv = tk ? mn : bv; bp = tk ? 4 * g + 3 : bp; } }

        FPS_GRP(0, md0,  md1,  md2,  md3)
        FPS_GRP(1, md4,  md5,  md6,  md7)
        FPS_GRP(2, md8,  md9,  md10, md11)
        FPS_GRP(3, md12, md13, md14, md15)
#undef FPS_GRP
#undef FPS_PT

        // wave64 argmax via DPP (combine idempotent: max, tie->min index)
#define RSTEP(C_) { float ov = dppf<C_>(bv); int op_ = dppi<C_>(bp);          \
                    bool tk = (ov > bv) || (ov == bv && op_ < bp);            \
                    bv = tk ? ov : bv; bp = tk ? op_ : bp; }
        RSTEP(0xB1)   // quad_perm [1,0,3,2]  : xor 1
        RSTEP(0x4E)   // quad_perm [2,3,0,1]  : xor 2
        RSTEP(0x141)  // row_half_mirror      : xor 4
        RSTEP(0x140)  // row_mirror           : xor 8
        RSTEP(0x142)  // row_bcast15          : rows 1,3 absorb rows 0,2
        RSTEP(0x143)  // row_bcast31          : upper half absorbs lower
#undef RSTEP

        const int par = m & 1;
        if ((t & 63) == 63) { s_bv[par][w] = bv; s_bp[par][w] = bp; }
        __syncthreads();

        // all threads redundantly pick the block winner (broadcast LDS reads)
        float gv = s_bv[par][0]; int gp = s_bp[par][0];
#pragma unroll
        for (int q = 1; q < FPS_W; ++q) {
            float ov = s_bv[par][q]; int op_ = s_bp[par][q];
            bool tk = (ov > gv) || (ov == gv && op_ < gp);
            gv = tk ? ov : gv; gp = tk ? op_ : gp;
        }
        const int grp = gp >> 2, cmp = gp & 3;
        lx = ((const float*)&sx4[grp])[cmp];
        ly = ((const float*)&sy4[grp])[cmp];
        lz = ((const float*)&sz4[grp])[cmp];
    }
}

// ---------------------------------------------------------------------------
// Kernel 2: exact top-64 (by (d2, idx) u64 key) within ball r=0.4 via
// histogram radix-select + O(C^2) exact ranking. Downstream max-aggregation
// is order-invariant, but ranks reproduce lax.top_k order anyway.
// ---------------------------------------------------------------------------
#define KNN_CAP 320

__global__ __launch_bounds__(256) void knn_kernel(const float* __restrict__ pos,
                                                  const float* __restrict__ pos_s,
                                                  int* __restrict__ nidx,
                                                  float* __restrict__ nd2,
                                                  int* __restrict__ ncnt) {
    const int c = blockIdx.x;
    const int b = c >> 11;              // c / MCENT
    const float* pb = pos + b * NPTS * 3;
    const int t = threadIdx.x;

    const float cx = pos_s[c * 3 + 0];
    const float cy = pos_s[c * 3 + 1];
    const float cz = pos_s[c * 3 + 2];

    __shared__ int hist[64];
    __shared__ int s_B64, s_total, s_cnt;
    __shared__ unsigned long long cand[KNN_CAP];

    if (t < 64) hist[t] = 0;
    if (t == 0) s_cnt = 0;
    __syncthreads();

    float d2r[32];
#pragma unroll
    for (int i = 0; i < 32; ++i) {
        int p = (i << 8) + t;
        float d2 = dist2(cx, cy, cz, pb[3 * p + 0], pb[3 * p + 1], pb[3 * p + 2]);
        d2r[i] = d2;
        if (d2 <= 0.16f) {
            int bkt = (int)(d2 * 400.0f);      // monotone; 0.16f*400 < 64
            bkt = bkt > 63 ? 63 : bkt;
            atomicAdd(&hist[bkt], 1);
        }
    }
    __syncthreads();

    if (t == 0) {
        int cum = 0, B = -1;
#pragma unroll
        for (int j = 0; j < 64; ++j) {
            cum += hist[j];
            if (B < 0 && cum >= 64) B = j;
        }
        s_B64 = (B < 0) ? 63 : B;
        s_total = cum;
    }
    __syncthreads();

    const int B64 = s_B64;
#pragma unroll
    for (int i = 0; i < 32; ++i) {
        float d2 = d2r[i];
        if (d2 <= 0.16f) {
            int bkt = (int)(d2 * 400.0f);
            bkt = bkt > 63 ? 63 : bkt;
            if (bkt <= B64) {
                int slot = atomicAdd(&s_cnt, 1);
                if (slot < KNN_CAP) {
                    int p = (i << 8) + t;
                    cand[slot] = ((unsigned long long)__float_as_uint(d2) << 32)
                                 | (unsigned int)p;
                }
            }
        }
    }
    __syncthreads();

    const int C = s_cnt < KNN_CAP ? s_cnt : KNN_CAP;
    // exact rank: candidate set is downward-closed, so candidate rank ==
    // global in-ball rank. Broadcast LDS reads (wave-uniform j).
    for (int tc = t; tc < C; tc += 256) {
        unsigned long long my = cand[tc];
        int rank = 0;
        for (int j = 0; j < C; ++j) rank += (cand[j] < my) ? 1 : 0;
        if (rank < KMAX) {
            nidx[c * KMAX + rank] = (int)(my & 0xffffffffULL);
            nd2[c * KMAX + rank]  = __uint_as_float((unsigned int)(my >> 32));
        }
    }
    if (t == 0) ncnt[c] = s_total < KMAX ? s_total : KMAX;
}

// ---------------------------------------------------------------------------
// Kernel 3: fused gather + 2-layer MLP + masked max per centroid.
// ---------------------------------------------------------------------------
template <int K, int C1, int C2, int OUTOFF>
__global__ __launch_bounds__(256, 2) void mlp_kernel(
        const float* __restrict__ x, const float* __restrict__ pos,
        const float* __restrict__ pos_s,
        const int* __restrict__ nidx, const float* __restrict__ nd2,
        const int* __restrict__ ncnt,
        const float* __restrict__ W1, const float* __restrict__ B1,
        const float* __restrict__ W2, const float* __restrict__ B2,
        float* __restrict__ out, float r2) {
    const int c = blockIdx.x;
    const int b = c >> 11;
    const int t = threadIdx.x;

    __shared__ float F[K][68];      // [K][67] padded to 17 float4
    __shared__ float H[K][C1];
    __shared__ int   s_nbr[K];
    __shared__ int   s_valid[K];
    __shared__ float s_ctr[3];

    const int cntAll = ncnt[c];
    const int cnt = cntAll < K ? cntAll : K;
    if (t < 3) s_ctr[t] = pos_s[c * 3 + t];
    if (t < K) {
        bool ok = t < cnt;
        s_nbr[t]   = ok ? nidx[c * KMAX + t] : 0;
        s_valid[t] = ok && (nd2[c * KMAX + t] <= r2);
    }
    __syncthreads();

    // gather features: F[k] = [ x[nbr] (64) | pos[nbr]-ctr (3) | 0 pad ]
    for (int e = t; e < K * 17; e += 256) {
        int k = e / 17, q = e % 17;
        int nbr = s_nbr[k];
        bool ok = k < cnt;
        float4 val;
        if (q < 16) {
            const float4* xr = (const float4*)(x + (b * NPTS + nbr) * CFEAT);
            if (ok) val = xr[q];
            else { val.x = 0.f; val.y = 0.f; val.z = 0.f; val.w = 0.f; }
        } else {
            const float* pp = pos + (b * NPTS + nbr) * 3;
            val.x = ok ? pp[0] - s_ctr[0] : 0.f;
            val.y = ok ? pp[1] - s_ctr[1] : 0.f;
            val.z = ok ? pp[2] - s_ctr[2] : 0.f;
            val.w = 0.f;
        }
        ((float4*)&F[k][0])[q] = val;
    }
    __syncthreads();

    // layer 1: H[k][j] = relu(B1[j] + F[k]·W1[:,j])
    {
        constexpr int STR = 256 / C1;
        const int j  = t % C1;
        const int kb = t / C1;
        float w1c[68];
#pragma unroll
        for (int i = 0; i < 67; ++i) w1c[i] = W1[i * C1 + j];
        w1c[67] = 0.f;
        const float bj = B1[j];
        for (int k = kb; k < K; k += STR) {
            float acc = bj;
            const float4* fr = (const float4*)&F[k][0];
#pragma unroll
            for (int q = 0; q < 17; ++q) {
                float4 f = fr[q];
                acc = fmaf(f.x, w1c[4 * q + 0], acc);
                acc = fmaf(f.y, w1c[4 * q + 1], acc);
                acc = fmaf(f.z, w1c[4 * q + 2], acc);
                acc = fmaf(f.w, w1c[4 * q + 3], acc);
            }
            H[k][j] = fmaxf(acc, 0.f);
        }
    }
    __syncthreads();

    // layer 2 + masked max over neighbors
    if constexpr (C2 == 256) {
        const int j2 = t;
        float w2c[C1];
#pragma unroll
        for (int i = 0; i < C1; ++i) w2c[i] = W2[i * C2 + j2];
        const float bj = B2[j2];
        float omax = NEGV;
        for (int k = 0; k < K; ++k) {
            if (!s_valid[k]) continue;          // uniform branch
            float acc = bj;
            const float4* hr = (const float4*)&H[k][0];
#pragma unroll
            for (int q = 0; q < C1 / 4; ++q) {
                float4 h = hr[q];
                acc = fmaf(h.x, w2c[4 * q + 0], acc);
                acc = fmaf(h.y, w2c[4 * q + 1], acc);
                acc = fmaf(h.z, w2c[4 * q + 2], acc);
                acc = fmaf(h.w, w2c[4 * q + 3], acc);
            }
            omax = fmaxf(omax, fmaxf(acc, 0.f));
        }
        out[c * 384 + OUTOFF + j2] = omax;
    } else {
        // C2 == 128: 2 thread-groups split the k range, combine via LDS
        const int j2 = t % C2;
        const int g  = t / C2;
        __shared__ float pm[256];
        float w2c[C1];
#pragma unroll
        for (int i = 0; i < C1; ++i) w2c[i] = W2[i * C2 + j2];
        const float bj = B2[j2];
        float omax = NEGV;
        for (int k = g; k < K; k += 2) {
            if (!s_valid[k]) continue;
            float acc = bj;
            const float4* hr = (const float4*)&H[k][0];
#pragma unroll
            for (int q = 0; q < C1 / 4; ++q) {
                float4 h = hr[q];
                acc = fmaf(h.x, w2c[4 * q + 0], acc);
                acc = fmaf(h.y, w2c[4 * q + 1], acc);
                acc = fmaf(h.z, w2c[4 * q + 2], acc);
                acc = fmaf(h.w, w2c[4 * q + 3], acc);
            }
            omax = fmaxf(omax, fmaxf(acc, 0.f));
        }
        pm[t] = omax;
        __syncthreads();
        if (t < C2) out[c * 384 + OUTOFF + t] = fmaxf(pm[t], pm[t + C2]);
    }
}

extern "C" void kernel_launch(void* const* d_in, const int* in_sizes, int n_in,
                              void* d_out, int out_size, void* d_ws, size_t ws_size,
                              hipStream_t stream) {
    const float* x    = (const float*)d_in[0];
    const float* pos  = (const float*)d_in[1];
    const float* w1_0 = (const float*)d_in[2];
    const float* b1_0 = (const float*)d_in[3];
    const float* w1_1 = (const float*)d_in[4];
    const float* b1_1 = (const float*)d_in[5];
    const float* w2_0 = (const float*)d_in[6];
    const float* b2_0 = (const float*)d_in[7];
    const float* w2_1 = (const float*)d_in[8];
    const float* b2_1 = (const float*)d_in[9];

    float* out   = (float*)d_out;
    float* pos_s = out + NCENT * 384;          // second output, written by FPS

    char* ws = (char*)d_ws;
    int*   ncnt = (int*)ws;                                   // NCENT ints
    int*   nidx = (int*)(ws + NCENT * 4);                     // NCENT*64 ints
    float* nd2  = (float*)(ws + NCENT * 4 + NCENT * KMAX * 4);// NCENT*64 floats

    fps_kernel<<<BATCH, FPS_T, 0, stream>>>(pos, pos_s);
    knn_kernel<<<NCENT, 256, 0, stream>>>(pos, pos_s, nidx, nd2, ncnt);
    mlp_kernel<32, 64, 128, 0><<<NCENT, 256, 0, stream>>>(
        x, pos, pos_s, nidx, nd2, ncnt, w1_0, b1_0, w1_1, b1_1, out, 0.04f);
    mlp_kernel<64, 128, 256, 128><<<NCENT, 256, 0, stream>>>(
        x, pos, pos_s, nidx, nd2, ncnt, w2_0, b2_0, w2_1, b2_1, out, 0.16f);
}